// Round 19
// baseline (22.023 us; speedup 1.0000x reference)
//
#include <hip/hip_runtime.h>
#include <math.h>

#define DIMQ 16
#define HID  128
#define SPB  64          // samples per block (8 waves; wave owns ONE h-tile, FOUR sample-tiles)
#define NTHREADS 512

typedef __attribute__((ext_vector_type(8))) _Float16 f16x8;  // MFMA A/B frag (4 VGPRs)
typedef __attribute__((ext_vector_type(4))) _Float16 f16x4;  // packed b64 store
typedef __attribute__((ext_vector_type(4))) float f32x4;     // MFMA acc
typedef __attribute__((ext_vector_type(2))) float v2f;       // packed f32 (v_pk_fma_f32)

// LDS layout (bytes): power-of-2 rows + XOR bank-skew (v17-validated). Mscr overlays ALL.
#define OFF_WFF  0       // f16 frag-major [8][4][16][8] = 8192
#define OFF_ABT  8192    // f16[16][256] XOR-swz = 8192 -> 16384
#define OFF_USP  16384   // f16[64][256] XOR-swz = 32768 -> 49152
#define OFF_SST  49152   // f16[64][128] XOR-swz = 16384 -> 65536
#define OFF_MSCR 0       // f32 64*320 = 81920 (overlay after barrier 2)
#define LDS_BYTES 81920  // x2 = 160 KiB exactly -> 2 blocks/CU, 16 waves/CU

// XOR bank-skew in 16B (8-f16) granules within a row; bijective, alignment-preserving.
__device__ __forceinline__ int axor(int row, int off) { return off ^ ((row & 7) << 3); }
// XOR-swizzle inside each sample's 320-f32 M-scratch (v7-validated).
__device__ __forceinline__ int mswz(int s, int off) {
    return s * 320 + (off ^ ((s & 7) << 2));
}
__device__ __forceinline__ f16x8 pack8(float4 a, float4 b) {
    f16x8 r;
    r[0]=(_Float16)a.x; r[1]=(_Float16)a.y; r[2]=(_Float16)a.z; r[3]=(_Float16)a.w;
    r[4]=(_Float16)b.x; r[5]=(_Float16)b.y; r[6]=(_Float16)b.z; r[7]=(_Float16)b.w;
    return r;
}

// cap-128 register regime (v14-proven): 4 waves/SIMD, 2 resident 8-wave blocks/CU.
__global__ __launch_bounds__(NTHREADS, 4)
void lag_accel_kernel(const float* __restrict__ y,    // [BATCH][32]
                      const float* __restrict__ W1,   // [128][32]
                      const float* __restrict__ b1,   // [128]
                      const float* __restrict__ w2,   // [128]
                      float* __restrict__ out)        // [BATCH][16]
{
    __shared__ __align__(16) char smem[LDS_BYTES];
    _Float16* Wff = (_Float16*)(smem + OFF_WFF);   // frag-major W1 rows
    _Float16* ABT = (_Float16*)(smem + OFF_ABT);   // [16][256]: [j][h]=A[h][j], [j][128+h]=B[h][j]
    _Float16* usp = (_Float16*)(smem + OFF_USP);   // [64][256]: u / -sp
    _Float16* sst = (_Float16*)(smem + OFF_SST);   // [64][128]: s

    const int tid = threadIdx.x;
    const long long s0 = (long long)blockIdx.x * SPB;

    const int wave = tid >> 6;
    const int lane = tid & 63;
    const int grp  = lane >> 4;      // MFMA quadrant (k-slice / D row-block)
    const int j    = lane & 15;      // MFMA m/n index (= sample index within tile)
    const int ht   = wave;           // this wave's h-tile

    // ---- y directly to registers: four 16-sample tiles (coalesced per wave) ----
    f16x8 yf[4];
#pragma unroll
    for (int st = 0; st < 4; ++st) {
        const float4* yg = (const float4*)(y + (s0 + st * 16 + j) * 32 + (grp << 3));
        yf[st] = pack8(yg[0], yg[1]);
    }

    // ---- staging (one b128 write per thread per array) ----
    {
        // Wff: 512 frag slots, slot = tid = ht*64 + grp*16 + j
        const int ht_ = tid >> 6, grp_ = (tid >> 4) & 3, j_ = tid & 15;
        const float4* src = (const float4*)(W1 + (ht_ * 16 + j_) * 32 + (grp_ << 3));
        *(f16x8*)&Wff[tid * 8] = pack8(src[0], src[1]);
    }
    {
        // ABT: column-wise loads -> contiguous b128 writes; tid = hb*32 + k
        const int k = tid & 31, h0 = (tid >> 5) << 3;
        float v[8];
#pragma unroll
        for (int i = 0; i < 8; ++i) v[i] = W1[(h0 + i) * 32 + k];
        f16x8 p;
#pragma unroll
        for (int i = 0; i < 8; ++i) p[i] = (_Float16)v[i];
        const int j_ = (k < 16) ? k : (k - 16);
        const int off = (k < 16) ? h0 : (128 + h0);
        *(f16x8*)&ABT[(j_ << 8) + axor(j_, off)] = p;
    }

    __syncthreads();   // barrier 0: Wff/ABT staged

    // ---- z/aqd GEMMs + elementwise, per sample-tile (sequential -> low reg peak) ----
    f16x8 aW  = *(const f16x8*)&Wff[((ht * 4 + grp) * 16 + j) * 8];
    f16x8 aAl = *(const f16x8*)&Wff[((ht * 4 + (grp & 1)) * 16 + j) * 8];
    f16x8 aA;
#pragma unroll
    for (int e = 0; e < 8; ++e) aA[e] = (grp >= 2) ? aAl[e] : (_Float16)0.0f;
    float4 b1v = *(const float4*)&b1[ht * 16 + (grp << 2)];
    float4 w2v = *(const float4*)&w2[ht * 16 + (grp << 2)];
    f32x4 ci; ci[0] = b1v.x; ci[1] = b1v.y; ci[2] = b1v.z; ci[3] = b1v.w;
    const f32x4 zf = {0.0f, 0.0f, 0.0f, 0.0f};
    const int h4 = ht * 16 + (grp << 2);

#pragma unroll
    for (int st = 0; st < 4; ++st) {
        f32x4 zacc = __builtin_amdgcn_mfma_f32_16x16x32_f16(aW, yf[st], ci, 0, 0, 0);
        f32x4 aacc = __builtin_amdgcn_mfma_f32_16x16x32_f16(aA, yf[st], zf, 0, 0, 0);
        const int smp2 = st * 16 + j;
        _Float16 su[4], sn[4], sv[4];
#pragma unroll
        for (int r = 0; r < 4; ++r) {
            float z  = zacc[r], aq = aacc[r];
            float w2c = (r == 0) ? w2v.x : (r == 1) ? w2v.y
                       : (r == 2) ? w2v.z : w2v.w;
            float e  = __expf(2.0f * z);
            float rr = 2.0f * __builtin_amdgcn_rcpf(e + 1.0f);
            float t_ = 1.0f - rr;
            float u  = w2c * (rr * (2.0f - rr));
            float s  = -2.0f * t_ * u;
            float sp = s * aq;
            su[r] = (_Float16)u; sn[r] = (_Float16)(-sp);
            sv[r] = (_Float16)s;
        }
        f16x4 pa = {su[0], su[1], su[2], su[3]};
        f16x4 pb = {sn[0], sn[1], sn[2], sn[3]};
        f16x4 pc = {sv[0], sv[1], sv[2], sv[3]};
        *(f16x4*)&usp[(smp2 << 8) + axor(smp2, h4)]       = pa;
        *(f16x4*)&usp[(smp2 << 8) + axor(smp2, 128 + h4)] = pb;
        *(f16x4*)&sst[(smp2 << 7) + axor(smp2, h4)]       = pc;
    }

    __syncthreads();   // barrier 1: u/-sp/s staged by all h-tiles

    // ---- rhs GEMM (waves 0-3): rhs = [A^T|B^T].[u;-sp], K=256 ----
    // D: lane (grp,j) holds rhs[4grp+r] of sample wave*16+j -> routed via Mscr col 16.
    f32x4 racc = {0.0f, 0.0f, 0.0f, 0.0f};
    if (wave < 4) {
        const int smp = wave * 16 + j;
#pragma unroll
        for (int kc = 0; kc < 8; ++kc) {
            const int o = (kc << 5) + (grp << 3);
            f16x8 af = *(const f16x8*)&ABT[(j << 8) + axor(j, o)];
            f16x8 bf = *(const f16x8*)&usp[(smp << 8) + axor(smp, o)];
            racc = __builtin_amdgcn_mfma_f32_16x16x32_f16(af, bf, racc, 0, 0, 0);
        }
    }

    // ---- M = I + B~^T diag(s) B~ via MFMA; wave's samples 8w..8w+7 ----
    f32x4 acc[8];
    {
        f32x4 ident;
#pragma unroll
        for (int r = 0; r < 4; ++r) ident[r] = ((grp << 2) + r == j) ? 1.0f : 0.0f;
#pragma unroll
        for (int gs = 0; gs < 8; ++gs) acc[gs] = ident;
    }
#pragma unroll
    for (int kc = 0; kc < 4; ++kc) {
        const int o = (kc << 5) + (grp << 3);
        f16x8 bfrag = *(const f16x8*)&ABT[(j << 8) + axor(j, 128 + o)];
#pragma unroll
        for (int gs = 0; gs < 8; ++gs) {
            const int smp = wave * 8 + gs;
            f16x8 sfrag = *(const f16x8*)&sst[(smp << 7) + axor(smp, o)];
            f16x8 afrag = sfrag * bfrag;   // v_pk_mul_f16 x4
            acc[gs] = __builtin_amdgcn_mfma_f32_16x16x32_f16(afrag, bfrag, acc[gs], 0, 0, 0);
        }
    }

    __syncthreads();   // barrier 2: all reads of Wff/ABT/usp/sst done -> Mscr overlay

    float* Mscr = (float*)(smem + OFF_MSCR);
    // M symmetric: D(rows 4grp..4grp+3, col j) == M[j][4grp..4grp+3] -> one b128/sample.
#pragma unroll
    for (int gs = 0; gs < 8; ++gs) {
        float4 v;
        v.x = acc[gs][0]; v.y = acc[gs][1]; v.z = acc[gs][2]; v.w = acc[gs][3];
        *(float4*)&Mscr[mswz(wave * 8 + gs, j * 20 + (grp << 2))] = v;
    }
    // rhs into col 16 of each sample's scratch (v7-validated slot).
    if (wave < 4) {
        const int smp = wave * 16 + j;
#pragma unroll
        for (int r = 0; r < 4; ++r)
            Mscr[mswz(smp, ((grp << 2) + r) * 20 + 16)] = racc[r];
    }

    __syncthreads();   // barrier 3: scratch complete

    // ---- solve (ALL 8 waves; 8 samples each; 8 lanes/sample, 2 rows/lane) ----
    const int sl = lane >> 3;            // sample within this wave's 8
    const int rw = lane & 7;             // lane owns rows rw and rw+8
    const int s  = wave * 8 + sl;        // sample within block

    v2f M2[2][8];
    float r2[2], d2[2];
#pragma unroll
    for (int rr = 0; rr < 2; ++rr) {
        const int row = rw + (rr << 3);
        const int ro = row * 20;
        float4 v0 = *(const float4*)&Mscr[mswz(s, ro + 0)];
        float4 v1 = *(const float4*)&Mscr[mswz(s, ro + 4)];
        float4 v2 = *(const float4*)&Mscr[mswz(s, ro + 8)];
        float4 v3 = *(const float4*)&Mscr[mswz(s, ro + 12)];
        M2[rr][0] = (v2f){v0.x, v0.y}; M2[rr][1] = (v2f){v0.z, v0.w};
        M2[rr][2] = (v2f){v1.x, v1.y}; M2[rr][3] = (v2f){v1.z, v1.w};
        M2[rr][4] = (v2f){v2.x, v2.y}; M2[rr][5] = (v2f){v2.z, v2.w};
        M2[rr][6] = (v2f){v3.x, v3.y}; M2[rr][7] = (v2f){v3.z, v3.w};
        r2[rr] = Mscr[mswz(s, ro + 16)];
        d2[rr] = 1.0f;
    }

    // Packed-f32 Gauss-Jordan, non-normalizing, triangular skip; row k owned by
    // lane (sl, k&7), register k>>3.
#pragma unroll
    for (int k = 0; k < 16; ++k) {
        const int src = (lane & 56) | (k & 7);   // same sample, owner row-lane
        const int kr = k >> 3;
        float piv = __shfl(M2[kr][k >> 1][k & 1], src, 64);
        float rk  = __shfl(r2[kr], src, 64);
        float invp = __builtin_amdgcn_rcpf(piv);
        invp = invp * (2.0f - piv * invp);
        float f0 = M2[0][k >> 1][k & 1] * invp;
        float f1 = M2[1][k >> 1][k & 1] * invp;
        const bool isk0 = (rw == k);
        const bool isk1 = (rw + 8 == k);
        f0 = isk0 ? 0.0f : f0;  d2[0] = isk0 ? piv : d2[0];
        f1 = isk1 ? 0.0f : f1;  d2[1] = isk1 ? piv : d2[1];
        r2[0] = fmaf(-f0, rk, r2[0]);
        r2[1] = fmaf(-f1, rk, r2[1]);
        const int i2s = (k >> 1) + (k & 1);
#pragma unroll
        for (int i2 = i2s; i2 < 8; ++i2) {
            float p0 = (2 * i2 == k) ? piv : __shfl(M2[kr][i2][0], src, 64);
            float p1 = __shfl(M2[kr][i2][1], src, 64);
            v2f pv = {p0, p1};
            v2f fv0 = {-f0, -f0};
            v2f fv1 = {-f1, -f1};
            M2[0][i2] = __builtin_elementwise_fma(fv0, pv, M2[0][i2]);
            M2[1][i2] = __builtin_elementwise_fma(fv1, pv, M2[1][i2]);
        }
    }

    {
        float i0 = __builtin_amdgcn_rcpf(d2[0]); i0 = i0 * (2.0f - d2[0] * i0);
        float i1 = __builtin_amdgcn_rcpf(d2[1]); i1 = i1 * (2.0f - d2[1] * i1);
        float* ob = out + (s0 + s) * DIMQ;
        ob[rw]     = r2[0] * i0;
        ob[rw + 8] = r2[1] * i1;
    }
}

extern "C" void kernel_launch(void* const* d_in, const int* in_sizes, int n_in,
                              void* d_out, int out_size, void* d_ws, size_t ws_size,
                              hipStream_t stream) {
    const float* y  = (const float*)d_in[0];
    const float* W1 = (const float*)d_in[1];
    const float* b1 = (const float*)d_in[2];
    const float* w2 = (const float*)d_in[3];
    float* out = (float*)d_out;
    const int batch = in_sizes[0] / 32;          // 32768
    const int blocks = (batch + SPB - 1) / SPB;  // 512
    lag_accel_kernel<<<blocks, NTHREADS, 0, stream>>>(y, W1, b1, w2, out);
}

// Round 20
// 19.016 us; speedup vs baseline: 1.1581x; 1.1581x over previous
//
#include <hip/hip_runtime.h>
#include <math.h>

#define DIMQ 16
#define HID  128
#define SPB  64          // samples per block (8 waves; wave owns ONE h-tile, FOUR sample-tiles)
#define NTHREADS 512

typedef __attribute__((ext_vector_type(8))) _Float16 f16x8;  // MFMA A/B frag (4 VGPRs)
typedef __attribute__((ext_vector_type(4))) _Float16 f16x4;  // packed b64 store
typedef __attribute__((ext_vector_type(4))) float f32x4;     // MFMA acc
typedef __attribute__((ext_vector_type(2))) float v2f;       // packed f32 (v_pk_fma_f32)

// LDS layout (bytes): power-of-2 rows + XOR bank-skew (v17-validated). Mscr overlays ALL.
#define OFF_WFF  0       // f16 frag-major [8][4][16][8] = 8192
#define OFF_ABT  8192    // f16[16][256] XOR-swz = 8192 -> 16384
#define OFF_USP  16384   // f16[64][256] XOR-swz = 32768 -> 49152
#define OFF_SST  49152   // f16[64][128] XOR-swz = 16384 -> 65536
#define OFF_MSCR 0       // f32 64*320 = 81920 (overlay after barrier 2)
#define LDS_BYTES 81920  // x2 = 160 KiB exactly -> 2 blocks/CU, 16 waves/CU

// XOR bank-skew in 16B (8-f16) granules within a row; bijective, alignment-preserving.
__device__ __forceinline__ int axor(int row, int off) { return off ^ ((row & 7) << 3); }
// XOR-swizzle inside each sample's 320-f32 M-scratch (v7-validated).
__device__ __forceinline__ int mswz(int s, int off) {
    return s * 320 + (off ^ ((s & 7) << 2));
}
__device__ __forceinline__ f16x8 pack8(float4 a, float4 b) {
    f16x8 r;
    r[0]=(_Float16)a.x; r[1]=(_Float16)a.y; r[2]=(_Float16)a.z; r[3]=(_Float16)a.w;
    r[4]=(_Float16)b.x; r[5]=(_Float16)b.y; r[6]=(_Float16)b.z; r[7]=(_Float16)b.w;
    return r;
}

// cap-128 register regime (v14-proven): 4 waves/SIMD, 2 resident 8-wave blocks/CU.
__global__ __launch_bounds__(NTHREADS, 4)
void lag_accel_kernel(const float* __restrict__ y,    // [BATCH][32]
                      const float* __restrict__ W1,   // [128][32]
                      const float* __restrict__ b1,   // [128]
                      const float* __restrict__ w2,   // [128]
                      float* __restrict__ out)        // [BATCH][16]
{
    __shared__ __align__(16) char smem[LDS_BYTES];
    _Float16* Wff = (_Float16*)(smem + OFF_WFF);   // frag-major W1 rows
    _Float16* ABT = (_Float16*)(smem + OFF_ABT);   // [16][256]: [j][h]=A[h][j], [j][128+h]=B[h][j]
    _Float16* usp = (_Float16*)(smem + OFF_USP);   // [64][256]: u / -sp
    _Float16* sst = (_Float16*)(smem + OFF_SST);   // [64][128]: s

    const int tid = threadIdx.x;
    const long long s0 = (long long)blockIdx.x * SPB;

    const int wave = tid >> 6;
    const int lane = tid & 63;
    const int grp  = lane >> 4;      // MFMA quadrant (k-slice / D row-block)
    const int j    = lane & 15;      // MFMA m/n index (= sample index within tile)
    const int ht   = wave;           // this wave's h-tile

    // ---- y directly to registers: four 16-sample tiles (coalesced per wave) ----
    f16x8 yf[4];
#pragma unroll
    for (int st = 0; st < 4; ++st) {
        const float4* yg = (const float4*)(y + (s0 + st * 16 + j) * 32 + (grp << 3));
        yf[st] = pack8(yg[0], yg[1]);
    }

    // ---- staging (one b128 write per thread per array) ----
    {
        // Wff: 512 frag slots, slot = tid = ht*64 + grp*16 + j
        const int ht_ = tid >> 6, grp_ = (tid >> 4) & 3, j_ = tid & 15;
        const float4* src = (const float4*)(W1 + (ht_ * 16 + j_) * 32 + (grp_ << 3));
        *(f16x8*)&Wff[tid * 8] = pack8(src[0], src[1]);
    }
    {
        // ABT: column-wise loads -> contiguous b128 writes; tid = hb*32 + k
        const int k = tid & 31, h0 = (tid >> 5) << 3;
        float v[8];
#pragma unroll
        for (int i = 0; i < 8; ++i) v[i] = W1[(h0 + i) * 32 + k];
        f16x8 p;
#pragma unroll
        for (int i = 0; i < 8; ++i) p[i] = (_Float16)v[i];
        const int j_ = (k < 16) ? k : (k - 16);
        const int off = (k < 16) ? h0 : (128 + h0);
        *(f16x8*)&ABT[(j_ << 8) + axor(j_, off)] = p;
    }

    __syncthreads();   // barrier 0: Wff/ABT staged

    // ---- z/aqd GEMMs + elementwise, per sample-tile (sequential -> low reg peak) ----
    f16x8 aW  = *(const f16x8*)&Wff[((ht * 4 + grp) * 16 + j) * 8];
    f16x8 aAl = *(const f16x8*)&Wff[((ht * 4 + (grp & 1)) * 16 + j) * 8];
    f16x8 aA;
#pragma unroll
    for (int e = 0; e < 8; ++e) aA[e] = (grp >= 2) ? aAl[e] : (_Float16)0.0f;
    float4 b1v = *(const float4*)&b1[ht * 16 + (grp << 2)];
    float4 w2v = *(const float4*)&w2[ht * 16 + (grp << 2)];
    f32x4 ci; ci[0] = b1v.x; ci[1] = b1v.y; ci[2] = b1v.z; ci[3] = b1v.w;
    const f32x4 zf = {0.0f, 0.0f, 0.0f, 0.0f};
    const int h4 = ht * 16 + (grp << 2);

#pragma unroll
    for (int st = 0; st < 4; ++st) {
        f32x4 zacc = __builtin_amdgcn_mfma_f32_16x16x32_f16(aW, yf[st], ci, 0, 0, 0);
        f32x4 aacc = __builtin_amdgcn_mfma_f32_16x16x32_f16(aA, yf[st], zf, 0, 0, 0);
        const int smp2 = st * 16 + j;
        _Float16 su[4], sn[4], sv[4];
#pragma unroll
        for (int r = 0; r < 4; ++r) {
            float z  = zacc[r], aq = aacc[r];
            float w2c = (r == 0) ? w2v.x : (r == 1) ? w2v.y
                       : (r == 2) ? w2v.z : w2v.w;
            float e  = __expf(2.0f * z);
            float rr = 2.0f * __builtin_amdgcn_rcpf(e + 1.0f);
            float t_ = 1.0f - rr;
            float u  = w2c * (rr * (2.0f - rr));
            float s  = -2.0f * t_ * u;
            float sp = s * aq;
            su[r] = (_Float16)u; sn[r] = (_Float16)(-sp);
            sv[r] = (_Float16)s;
        }
        f16x4 pa = {su[0], su[1], su[2], su[3]};
        f16x4 pb = {sn[0], sn[1], sn[2], sn[3]};
        f16x4 pc = {sv[0], sv[1], sv[2], sv[3]};
        *(f16x4*)&usp[(smp2 << 8) + axor(smp2, h4)]       = pa;
        *(f16x4*)&usp[(smp2 << 8) + axor(smp2, 128 + h4)] = pb;
        *(f16x4*)&sst[(smp2 << 7) + axor(smp2, h4)]       = pc;
    }

    __syncthreads();   // barrier 1: u/-sp/s staged by all h-tiles

    // ---- rhs GEMM (waves 0-3): rhs = [A^T|B^T].[u;-sp], K=256; D lands in solve layout ----
    f32x4 racc = {0.0f, 0.0f, 0.0f, 0.0f};
    if (wave < 4) {
        const int smp = wave * 16 + j;
#pragma unroll
        for (int kc = 0; kc < 8; ++kc) {
            const int o = (kc << 5) + (grp << 3);
            f16x8 af = *(const f16x8*)&ABT[(j << 8) + axor(j, o)];
            f16x8 bf = *(const f16x8*)&usp[(smp << 8) + axor(smp, o)];
            racc = __builtin_amdgcn_mfma_f32_16x16x32_f16(af, bf, racc, 0, 0, 0);
        }
    }

    // ---- M = I + B~^T diag(s) B~ via MFMA; wave's samples 8w..8w+7 ----
    f32x4 acc[8];
    {
        f32x4 ident;
#pragma unroll
        for (int r = 0; r < 4; ++r) ident[r] = ((grp << 2) + r == j) ? 1.0f : 0.0f;
#pragma unroll
        for (int gs = 0; gs < 8; ++gs) acc[gs] = ident;
    }
#pragma unroll
    for (int kc = 0; kc < 4; ++kc) {
        const int o = (kc << 5) + (grp << 3);
        f16x8 bfrag = *(const f16x8*)&ABT[(j << 8) + axor(j, 128 + o)];
#pragma unroll
        for (int gs = 0; gs < 8; ++gs) {
            const int smp = wave * 8 + gs;
            f16x8 sfrag = *(const f16x8*)&sst[(smp << 7) + axor(smp, o)];
            f16x8 afrag = sfrag * bfrag;   // v_pk_mul_f16 x4
            acc[gs] = __builtin_amdgcn_mfma_f32_16x16x32_f16(afrag, bfrag, acc[gs], 0, 0, 0);
        }
    }

    __syncthreads();   // barrier 2: all reads of Wff/ABT/usp/sst done -> Mscr overlay

    float* Mscr = (float*)(smem + OFF_MSCR);
    // M symmetric: D(rows 4grp..4grp+3, col j) == M[j][4grp..4grp+3] -> one b128/sample.
#pragma unroll
    for (int gs = 0; gs < 8; ++gs) {
        float4 v;
        v.x = acc[gs][0]; v.y = acc[gs][1]; v.z = acc[gs][2]; v.w = acc[gs][3];
        *(float4*)&Mscr[mswz(wave * 8 + gs, j * 20 + (grp << 2))] = v;
    }

    __syncthreads();   // barrier 3: scratch complete

    // ---- solve (waves 0-3; 16 samples each; 4 lanes/sample, 4 rows/lane) ----
    if (wave >= 4) return;
    const int sl = lane & 15;            // sample within this wave's quarter
    const int rb = lane >> 4;            // row block (rows 4rb..4rb+3)
    const int s  = wave * 16 + sl;       // sample within block

    v2f M2[4][8];
    float r4[4], d4[4];
#pragma unroll
    for (int r = 0; r < 4; ++r) {
        const int ro = (4 * rb + r) * 20;
        float4 v0 = *(const float4*)&Mscr[mswz(s, ro + 0)];
        float4 v1 = *(const float4*)&Mscr[mswz(s, ro + 4)];
        float4 v2 = *(const float4*)&Mscr[mswz(s, ro + 8)];
        float4 v3 = *(const float4*)&Mscr[mswz(s, ro + 12)];
        M2[r][0] = (v2f){v0.x, v0.y}; M2[r][1] = (v2f){v0.z, v0.w};
        M2[r][2] = (v2f){v1.x, v1.y}; M2[r][3] = (v2f){v1.z, v1.w};
        M2[r][4] = (v2f){v2.x, v2.y}; M2[r][5] = (v2f){v2.z, v2.w};
        M2[r][6] = (v2f){v3.x, v3.y}; M2[r][7] = (v2f){v3.z, v3.w};
        r4[r] = racc[r];                 // rhs already in the right lane/reg
        d4[r] = 1.0f;
    }

    // Packed-f32 Gauss-Jordan (v14-validated), non-normalizing, triangular skip.
#pragma unroll
    for (int k = 0; k < 16; ++k) {
        const int src = sl + ((k >> 2) << 4);
        float piv = __shfl(M2[k & 3][k >> 1][k & 1], src, 64);
        float rk  = __shfl(r4[k & 3], src, 64);
        float invp = __builtin_amdgcn_rcpf(piv);
        invp = invp * (2.0f - piv * invp);
        float f[4];
#pragma unroll
        for (int r = 0; r < 4; ++r) {
            float fr = M2[r][k >> 1][k & 1] * invp;
            const bool isk = ((rb << 2) + r) == k;
            f[r]  = isk ? 0.0f : fr;
            d4[r] = isk ? piv : d4[r];
            r4[r] = fmaf(-f[r], rk, r4[r]);
        }
        const int i2s = (k >> 1) + (k & 1);
#pragma unroll
        for (int i2 = i2s; i2 < 8; ++i2) {
            float p0 = (2 * i2 == k) ? piv : __shfl(M2[k & 3][i2][0], src, 64);
            float p1 = __shfl(M2[k & 3][i2][1], src, 64);
            v2f pv = {p0, p1};
#pragma unroll
            for (int r = 0; r < 4; ++r) {
                v2f fv = {-f[r], -f[r]};
                M2[r][i2] = __builtin_elementwise_fma(fv, pv, M2[r][i2]);
            }
        }
    }

    float4 xo;
    {
        float i0 = __builtin_amdgcn_rcpf(d4[0]); i0 = i0 * (2.0f - d4[0] * i0);
        float i1 = __builtin_amdgcn_rcpf(d4[1]); i1 = i1 * (2.0f - d4[1] * i1);
        float i2 = __builtin_amdgcn_rcpf(d4[2]); i2 = i2 * (2.0f - d4[2] * i2);
        float i3 = __builtin_amdgcn_rcpf(d4[3]); i3 = i3 * (2.0f - d4[3] * i3);
        xo.x = r4[0] * i0; xo.y = r4[1] * i1; xo.z = r4[2] * i2; xo.w = r4[3] * i3;
    }
    *(float4*)&out[(s0 + s) * DIMQ + (rb << 2)] = xo;
}

extern "C" void kernel_launch(void* const* d_in, const int* in_sizes, int n_in,
                              void* d_out, int out_size, void* d_ws, size_t ws_size,
                              hipStream_t stream) {
    const float* y  = (const float*)d_in[0];
    const float* W1 = (const float*)d_in[1];
    const float* b1 = (const float*)d_in[2];
    const float* w2 = (const float*)d_in[3];
    float* out = (float*)d_out;
    const int batch = in_sizes[0] / 32;          // 32768
    const int blocks = (batch + SPB - 1) / SPB;  // 512
    lag_accel_kernel<<<blocks, NTHREADS, 0, stream>>>(y, W1, b1, w2, out);
}